// Round 2
// baseline (79.085 us; speedup 1.0000x reference)
//
#include <hip/hip_runtime.h>
#include <math.h>

#define B_ 512
#define C_ 512
#define D_ 512

// c = clip(softplus(raw_c) + 1e-6, 1e-4, 1e4), computed stably per-thread (scalar input)
__device__ __forceinline__ float compute_c(const float* raw_c) {
    float rc = raw_c[0];
    float sp = fmaxf(rc, 0.0f) + log1pf(expf(-fabsf(rc)));  // stable softplus
    float c = sp + 1e-6f;
    return fminf(fmaxf(c, 1e-4f), 1e4f);
}

// One wave (64 lanes) per row. Computes expmap0 scaling and squared norm of the
// mapped point. Handles both feats (rows 0..B-1) and protos (rows B..B+C-1).
__global__ __launch_bounds__(64) void prep_kernel(
    const float* __restrict__ feats, const float* __restrict__ protos,
    const float* __restrict__ raw_c,
    float* __restrict__ z, float* __restrict__ p,
    float* __restrict__ x2, float* __restrict__ y2)
{
    int row = blockIdx.x;
    const float* src;
    float* dst;
    float* sq;
    int r;
    if (row < B_) { r = row;      src = feats  + (size_t)r * D_; dst = z + (size_t)r * D_; sq = x2; }
    else          { r = row - B_; src = protos + (size_t)r * D_; dst = p + (size_t)r * D_; sq = y2; }

    float c = compute_c(raw_c);
    float scc = sqrtf(c);

    int lane = threadIdx.x;                 // 0..63
    const float4* s4 = (const float4*)src;  // 512 floats = 128 float4
    float4 v0 = s4[lane];
    float4 v1 = s4[lane + 64];
    float ss = v0.x*v0.x + v0.y*v0.y + v0.z*v0.z + v0.w*v0.w
             + v1.x*v1.x + v1.y*v1.y + v1.z*v1.z + v1.w*v1.w;
    #pragma unroll
    for (int off = 32; off > 0; off >>= 1) ss += __shfl_xor(ss, off);

    float n = fmaxf(sqrtf(ss), 1e-15f);     // NORM_EPS
    float s = tanhf(scc * n) / (scc * n);   // expmap0 scale factor

    float4* d4 = (float4*)dst;
    d4[lane]      = make_float4(v0.x*s, v0.y*s, v0.z*s, v0.w*s);
    d4[lane + 64] = make_float4(v1.x*s, v1.y*s, v1.z*s, v1.w*s);
    if (lane == 0) sq[r] = s * s * ss;      // ||mapped point||^2 (exact: s^2 * ||u||^2)
}

// Per-output epilogue: mobius_add norm via the quadratic form, then artanh.
__device__ __forceinline__ float dist_val(float zp, float x2, float y2,
                                          float c, float scc, float inv_sc) {
    float xy = -zp;                               // <x, p> with x = -z
    float two_cxy = 2.0f * c * xy;
    float a = 1.0f + two_cxy + c * y2;
    float b = 1.0f - c * x2;
    float den = fmaxf(1.0f + two_cxy + c * c * x2 * y2, 1e-15f);
    float num2 = a * a * x2 + 2.0f * a * b * xy + b * b * y2;  // ||a*x + b*p||^2
    float mn = sqrtf(fmaxf(num2, 0.0f)) / den;
    float t = fminf(scc * mn, 1.0f - 1e-7f);      // t >= 0, so only upper clip binds
    // 2/sc * artanh(t) = (1/sc) * log((1+t)/(1-t))
    return -inv_sc * logf((1.0f + t) / (1.0f - t));
}

// 32x32 output tile per 256-thread block; BK=32 LDS staging (+1 pad); 2x2 per thread.
__global__ __launch_bounds__(256) void dist_kernel(
    const float* __restrict__ z, const float* __restrict__ p,
    const float* __restrict__ x2v, const float* __restrict__ y2v,
    const float* __restrict__ raw_c, float* __restrict__ out)
{
    __shared__ float As[32][33];
    __shared__ float Bs[32][33];

    int t  = threadIdx.x;
    int tx = t & 15;        // 0..15
    int ty = t >> 4;        // 0..15
    int row0 = blockIdx.y * 32;
    int col0 = blockIdx.x * 32;

    int lrow = t >> 3;          // 0..31 (staging row)
    int lc4  = (t & 7) * 4;     // 0,4,...,28 (staging col)

    float acc00 = 0.f, acc01 = 0.f, acc10 = 0.f, acc11 = 0.f;

    for (int k0 = 0; k0 < D_; k0 += 32) {
        float4 av = *(const float4*)(z + (size_t)(row0 + lrow) * D_ + k0 + lc4);
        float4 bv = *(const float4*)(p + (size_t)(col0 + lrow) * D_ + k0 + lc4);
        __syncthreads();  // protect previous iteration's reads
        As[lrow][lc4+0] = av.x; As[lrow][lc4+1] = av.y;
        As[lrow][lc4+2] = av.z; As[lrow][lc4+3] = av.w;
        Bs[lrow][lc4+0] = bv.x; Bs[lrow][lc4+1] = bv.y;
        Bs[lrow][lc4+2] = bv.z; Bs[lrow][lc4+3] = bv.w;
        __syncthreads();
        #pragma unroll
        for (int k = 0; k < 32; ++k) {
            float a0 = As[ty][k],      a1 = As[ty + 16][k];
            float b0 = Bs[tx][k],      b1 = Bs[tx + 16][k];
            acc00 = fmaf(a0, b0, acc00);
            acc01 = fmaf(a0, b1, acc01);
            acc10 = fmaf(a1, b0, acc10);
            acc11 = fmaf(a1, b1, acc11);
        }
    }

    float c = compute_c(raw_c);
    float scc = sqrtf(c);
    float inv_sc = 1.0f / scc;

    int i0 = row0 + ty, i1 = row0 + ty + 16;
    int j0 = col0 + tx, j1 = col0 + tx + 16;
    float x2_0 = x2v[i0], x2_1 = x2v[i1];
    float y2_0 = y2v[j0], y2_1 = y2v[j1];

    out[(size_t)i0 * C_ + j0] = dist_val(acc00, x2_0, y2_0, c, scc, inv_sc);
    out[(size_t)i0 * C_ + j1] = dist_val(acc01, x2_0, y2_1, c, scc, inv_sc);
    out[(size_t)i1 * C_ + j0] = dist_val(acc10, x2_1, y2_0, c, scc, inv_sc);
    out[(size_t)i1 * C_ + j1] = dist_val(acc11, x2_1, y2_1, c, scc, inv_sc);
}

extern "C" void kernel_launch(void* const* d_in, const int* in_sizes, int n_in,
                              void* d_out, int out_size, void* d_ws, size_t ws_size,
                              hipStream_t stream) {
    const float* feats  = (const float*)d_in[0];
    const float* protos = (const float*)d_in[1];
    const float* raw_c  = (const float*)d_in[2];
    float* out = (float*)d_out;

    float* z  = (float*)d_ws;          // B*D
    float* p  = z + (size_t)B_ * D_;   // C*D
    float* x2 = p + (size_t)C_ * D_;   // B
    float* y2 = x2 + B_;               // C

    prep_kernel<<<B_ + C_, 64, 0, stream>>>(feats, protos, raw_c, z, p, x2, y2);

    dim3 grid(C_ / 32, B_ / 32);
    dist_kernel<<<grid, 256, 0, stream>>>(z, p, x2, y2, raw_c, out);
}

// Round 3
// 66.622 us; speedup vs baseline: 1.1871x; 1.1871x over previous
//
#include <hip/hip_runtime.h>
#include <math.h>

#define B_ 512
#define C_ 512
#define D_ 512
#define LDK 520   // LDS row stride in bf16 elems: 512 + 8 pad -> 2-way bank alias only (free)

typedef __attribute__((ext_vector_type(8))) short s8v;   // 8 bf16 = 4 VGPR (MFMA A/B frag)
typedef __attribute__((ext_vector_type(4))) short s4v;   // 8-byte LDS store
typedef __attribute__((ext_vector_type(4))) float f4v;   // MFMA acc

__device__ __forceinline__ float compute_c_dev(float rc) {
    float sp = fmaxf(rc, 0.0f) + log1pf(expf(-fabsf(rc)));  // stable softplus
    float c = sp + 1e-6f;
    return fminf(fmaxf(c, 1e-4f), 1e4f);
}

__device__ __forceinline__ unsigned short f2bf(float f) {  // RNE fp32 -> bf16
    unsigned u = __float_as_uint(f);
    u += 0x7FFFu + ((u >> 16) & 1u);
    return (unsigned short)(u >> 16);
}

__device__ __forceinline__ float dist_val(float zp, float x2, float y2,
                                          float c, float scc, float inv_sc) {
    float xy = -zp;                               // <x,p>, x = -z
    float two_cxy = 2.0f * c * xy;
    float a = 1.0f + two_cxy + c * y2;
    float b = 1.0f - c * x2;
    float den = fmaxf(1.0f + two_cxy + c * c * x2 * y2, 1e-15f);
    float num2 = a * a * x2 + 2.0f * a * b * xy + b * b * y2;  // ||a*x + b*p||^2 exactly
    float mn = sqrtf(fmaxf(num2, 0.0f)) / den;
    float t = fminf(scc * mn, 1.0f - 1e-7f);      // t >= 0: only upper clip binds
    return -inv_sc * logf((1.0f + t) / (1.0f - t));  // -(2/sc)*artanh(t)
}

__global__ __launch_bounds__(256, 1) void fused_kernel(
    const float* __restrict__ feats, const float* __restrict__ protos,
    const float* __restrict__ raw_c, float* __restrict__ out)
{
    __shared__ short zs[32 * LDK];   // bf16 A tile (feats after expmap0)
    __shared__ short ps[32 * LDK];   // bf16 B tile (protos after expmap0)
    __shared__ float x2s[32];
    __shared__ float y2s[32];

    const int t    = threadIdx.x;
    const int lane = t & 63;
    const int w    = t >> 6;              // wave 0..3
    const int row0 = blockIdx.y * 32;
    const int col0 = blockIdx.x * 32;

    const float c      = compute_c_dev(raw_c[0]);
    const float scc    = sqrtf(c);
    const float inv_sc = 1.0f / scc;

    // ---- phase 1: expmap0 both tiles -> LDS (bf16), squared norms -> x2s/y2s ----
    // wave w owns A rows 8w..8w+7 and B rows 8w..8w+7 of this block's tiles.
    {
        const float4* srcA = (const float4*)(feats + (size_t)(row0 + 8 * w) * D_);
        float4 v0[8], v1[8];
        #pragma unroll
        for (int i = 0; i < 8; ++i) {         // issue all 16 loads first (MLP)
            v0[i] = srcA[i * 128 + lane];     // k = 4*lane .. +3
            v1[i] = srcA[i * 128 + lane + 64];// k = 256 + 4*lane .. +3
        }
        #pragma unroll
        for (int i = 0; i < 8; ++i) {
            int r = 8 * w + i;
            float ss = v0[i].x*v0[i].x + v0[i].y*v0[i].y + v0[i].z*v0[i].z + v0[i].w*v0[i].w
                     + v1[i].x*v1[i].x + v1[i].y*v1[i].y + v1[i].z*v1[i].z + v1[i].w*v1[i].w;
            #pragma unroll
            for (int off = 32; off > 0; off >>= 1) ss += __shfl_xor(ss, off);
            float n = fmaxf(sqrtf(ss), 1e-15f);
            float s = tanhf(scc * n) / (scc * n);
            if (lane == 0) x2s[r] = s * s * ss;
            s4v lo, hi;
            lo[0]=(short)f2bf(v0[i].x); lo[1]=(short)f2bf(v0[i].y);
            lo[2]=(short)f2bf(v0[i].z); lo[3]=(short)f2bf(v0[i].w);
            hi[0]=(short)f2bf(v1[i].x); hi[1]=(short)f2bf(v1[i].y);
            hi[2]=(short)f2bf(v1[i].z); hi[3]=(short)f2bf(v1[i].w);
            // note: scale s folded via bf16 of s*v — do multiply before convert
            lo[0]=(short)f2bf(v0[i].x*s); lo[1]=(short)f2bf(v0[i].y*s);
            lo[2]=(short)f2bf(v0[i].z*s); lo[3]=(short)f2bf(v0[i].w*s);
            hi[0]=(short)f2bf(v1[i].x*s); hi[1]=(short)f2bf(v1[i].y*s);
            hi[2]=(short)f2bf(v1[i].z*s); hi[3]=(short)f2bf(v1[i].w*s);
            *(s4v*)(&zs[r * LDK + 4 * lane])       = lo;
            *(s4v*)(&zs[r * LDK + 256 + 4 * lane]) = hi;
        }
    }
    {
        const float4* srcB = (const float4*)(protos + (size_t)(col0 + 8 * w) * D_);
        float4 v0[8], v1[8];
        #pragma unroll
        for (int i = 0; i < 8; ++i) {
            v0[i] = srcB[i * 128 + lane];
            v1[i] = srcB[i * 128 + lane + 64];
        }
        #pragma unroll
        for (int i = 0; i < 8; ++i) {
            int r = 8 * w + i;
            float ss = v0[i].x*v0[i].x + v0[i].y*v0[i].y + v0[i].z*v0[i].z + v0[i].w*v0[i].w
                     + v1[i].x*v1[i].x + v1[i].y*v1[i].y + v1[i].z*v1[i].z + v1[i].w*v1[i].w;
            #pragma unroll
            for (int off = 32; off > 0; off >>= 1) ss += __shfl_xor(ss, off);
            float n = fmaxf(sqrtf(ss), 1e-15f);
            float s = tanhf(scc * n) / (scc * n);
            if (lane == 0) y2s[r] = s * s * ss;
            s4v lo, hi;
            lo[0]=(short)f2bf(v0[i].x*s); lo[1]=(short)f2bf(v0[i].y*s);
            lo[2]=(short)f2bf(v0[i].z*s); lo[3]=(short)f2bf(v0[i].w*s);
            hi[0]=(short)f2bf(v1[i].x*s); hi[1]=(short)f2bf(v1[i].y*s);
            hi[2]=(short)f2bf(v1[i].z*s); hi[3]=(short)f2bf(v1[i].w*s);
            *(s4v*)(&ps[r * LDK + 4 * lane])       = lo;
            *(s4v*)(&ps[r * LDK + 256 + 4 * lane]) = hi;
        }
    }

    __syncthreads();

    // ---- phase 2: MFMA GEMM, wave w -> 16x16 quadrant (wr, wc) ----
    const int wr = w >> 1, wc = w & 1;
    const int rowA = 16 * wr + (lane & 15);
    const int rowB = 16 * wc + (lane & 15);
    const short* za = &zs[rowA * LDK + 8 * (lane >> 4)];
    const short* pa = &ps[rowB * LDK + 8 * (lane >> 4)];

    f4v acc = {0.f, 0.f, 0.f, 0.f};
    #pragma unroll
    for (int kk = 0; kk < 16; ++kk) {
        s8v af = *(const s8v*)(za + kk * 32);   // ds_read_b128
        s8v bf = *(const s8v*)(pa + kk * 32);
        acc = __builtin_amdgcn_mfma_f32_16x16x32_bf16(af, bf, acc, 0, 0, 0);
    }

    // ---- epilogue: C/D layout col=lane&15, row=4*(lane>>4)+reg (m89-verified) ----
    const int col   = lane & 15;
    const int rbase = 4 * (lane >> 4);
    const int gcol  = col0 + 16 * wc + col;
    const float y2  = y2s[16 * wc + col];
    #pragma unroll
    for (int r = 0; r < 4; ++r) {
        int lrow = 16 * wr + rbase + r;
        float x2 = x2s[lrow];
        out[(size_t)(row0 + lrow) * C_ + gcol] = dist_val(acc[r], x2, y2, c, scc, inv_sc);
    }
}

extern "C" void kernel_launch(void* const* d_in, const int* in_sizes, int n_in,
                              void* d_out, int out_size, void* d_ws, size_t ws_size,
                              hipStream_t stream) {
    const float* feats  = (const float*)d_in[0];
    const float* protos = (const float*)d_in[1];
    const float* raw_c  = (const float*)d_in[2];
    float* out = (float*)d_out;

    dim3 grid(C_ / 32, B_ / 32);
    fused_kernel<<<grid, 256, 0, stream>>>(feats, protos, raw_c, out);
}

// Round 4
// 63.620 us; speedup vs baseline: 1.2431x; 1.0472x over previous
//
#include <hip/hip_runtime.h>
#include <math.h>

#define B_ 512
#define C_ 512
#define D_ 512
#define LDK 520   // LDS row stride in bf16 elems: 512 + 8 pad -> 2-way bank alias only (free)

typedef __attribute__((ext_vector_type(8))) short s8v;   // 8 bf16 = 4 VGPR (MFMA A/B frag)
typedef __attribute__((ext_vector_type(4))) short s4v;   // 8-byte LDS store
typedef __attribute__((ext_vector_type(4))) float f4v;   // MFMA acc

__device__ __forceinline__ float compute_c_dev(float rc) {
    float sp = fmaxf(rc, 0.0f) + log1pf(expf(-fabsf(rc)));  // stable softplus (once/thread)
    float c = sp + 1e-6f;
    return fminf(fmaxf(c, 1e-4f), 1e4f);
}

__device__ __forceinline__ unsigned short f2bf(float f) {  // RNE fp32 -> bf16
    unsigned u = __float_as_uint(f);
    u += 0x7FFFu + ((u >> 16) & 1u);
    return (unsigned short)(u >> 16);
}

// tanh(x) for x>0 via fast exp: tanh = 1 - 2/(e^{2x}+1)
__device__ __forceinline__ float fast_tanh_pos(float x) {
    float e = __expf(2.0f * x);
    return 1.0f - __fdividef(2.0f, e + 1.0f);
}

__device__ __forceinline__ float dist_val(float zp, float x2, float y2,
                                          float c, float scc, float inv_sc) {
    float xy = -zp;                               // <x,p>, x = -z
    float two_cxy = 2.0f * c * xy;
    float a = 1.0f + two_cxy + c * y2;
    float b = 1.0f - c * x2;
    float den = fmaxf(1.0f + two_cxy + c * c * x2 * y2, 1e-15f);
    float num2 = a * a * x2 + 2.0f * a * b * xy + b * b * y2;  // ||a*x + b*p||^2 exactly
    float mn = __fdividef(sqrtf(fmaxf(num2, 0.0f)), den);
    float t = fminf(scc * mn, 1.0f - 1e-7f);      // t >= 0: only upper clip binds
    return -inv_sc * __logf(__fdividef(1.0f + t, 1.0f - t));  // -(2/sc)*artanh(t)
}

// 512 threads = 8 waves. Phase 1: each wave expmap0's 8 rows (waves 0-3: feats,
// waves 4-7: protos). Phase 2: split-K MFMA — wave {q, khalf} computes quadrant
// q over K-half khalf; halves combined via LDS. 2 waves/SIMD for latency hiding.
__global__ __launch_bounds__(512, 2) void fused_kernel(
    const float* __restrict__ feats, const float* __restrict__ protos,
    const float* __restrict__ raw_c, float* __restrict__ out)
{
    __shared__ short zs[32 * LDK];   // bf16 A tile (feats after expmap0)
    __shared__ short ps[32 * LDK];   // bf16 B tile (protos after expmap0)
    __shared__ float x2s[32];
    __shared__ float y2s[32];
    __shared__ f4v  accbuf[256];     // K-half partial sums (4 KB)

    const int t    = threadIdx.x;
    const int lane = t & 63;
    const int w    = t >> 6;              // wave 0..7
    const int row0 = blockIdx.y * 32;
    const int col0 = blockIdx.x * 32;

    const float c      = compute_c_dev(raw_c[0]);
    const float scc    = sqrtf(c);
    const float inv_sc = 1.0f / scc;

    // ---- phase 1: expmap0 both tiles -> LDS (bf16), squared norms -> x2s/y2s ----
    {
        const bool  isB = (w >= 4);
        const int   wl  = isB ? (w - 4) : w;   // 0..3
        const float* src = isB ? (protos + (size_t)(col0 + 8 * wl) * D_)
                               : (feats  + (size_t)(row0 + 8 * wl) * D_);
        short* dst = isB ? ps : zs;
        float* sqv = isB ? y2s : x2s;

        const float4* s4 = (const float4*)src;
        float4 v0[8], v1[8];
        #pragma unroll
        for (int i = 0; i < 8; ++i) {          // issue all 16 loads first (MLP)
            v0[i] = s4[i * 128 + lane];        // k = 4*lane .. +3
            v1[i] = s4[i * 128 + lane + 64];   // k = 256 + 4*lane .. +3
        }
        #pragma unroll
        for (int i = 0; i < 8; ++i) {
            int r = 8 * wl + i;
            float ss = v0[i].x*v0[i].x + v0[i].y*v0[i].y + v0[i].z*v0[i].z + v0[i].w*v0[i].w
                     + v1[i].x*v1[i].x + v1[i].y*v1[i].y + v1[i].z*v1[i].z + v1[i].w*v1[i].w;
            #pragma unroll
            for (int off = 32; off > 0; off >>= 1) ss += __shfl_xor(ss, off);
            float n = fmaxf(sqrtf(ss), 1e-15f);
            float arg = scc * n;
            float s = __fdividef(fast_tanh_pos(arg), arg);   // expmap0 scale
            if (lane == 0) sqv[r] = s * s * ss;              // ||mapped||^2 exactly
            s4v lo, hi;
            lo[0]=(short)f2bf(v0[i].x*s); lo[1]=(short)f2bf(v0[i].y*s);
            lo[2]=(short)f2bf(v0[i].z*s); lo[3]=(short)f2bf(v0[i].w*s);
            hi[0]=(short)f2bf(v1[i].x*s); hi[1]=(short)f2bf(v1[i].y*s);
            hi[2]=(short)f2bf(v1[i].z*s); hi[3]=(short)f2bf(v1[i].w*s);
            *(s4v*)(&dst[r * LDK + 4 * lane])       = lo;
            *(s4v*)(&dst[r * LDK + 256 + 4 * lane]) = hi;
        }
    }

    __syncthreads();

    // ---- phase 2: split-K MFMA. wave = {quadrant q, K-half khalf} ----
    const int q     = w & 3;
    const int khalf = w >> 2;
    const int wr = q >> 1, wc = q & 1;
    const int rowA = 16 * wr + (lane & 15);
    const int rowB = 16 * wc + (lane & 15);
    const short* za = &zs[rowA * LDK + 8 * (lane >> 4) + khalf * 256];
    const short* pa = &ps[rowB * LDK + 8 * (lane >> 4) + khalf * 256];

    f4v acc = {0.f, 0.f, 0.f, 0.f};
    #pragma unroll
    for (int kk = 0; kk < 8; ++kk) {
        s8v af = *(const s8v*)(za + kk * 32);   // ds_read_b128
        s8v bf = *(const s8v*)(pa + kk * 32);
        acc = __builtin_amdgcn_mfma_f32_16x16x32_bf16(af, bf, acc, 0, 0, 0);
    }

    if (khalf) accbuf[q * 64 + lane] = acc;
    __syncthreads();

    if (!khalf) {
        acc += accbuf[q * 64 + lane];
        // C/D layout: col=lane&15, row=4*(lane>>4)+reg (m89-verified)
        const int col   = lane & 15;
        const int rbase = 4 * (lane >> 4);
        const int gcol  = col0 + 16 * wc + col;
        const float y2  = y2s[16 * wc + col];
        #pragma unroll
        for (int r = 0; r < 4; ++r) {
            int lrow = 16 * wr + rbase + r;
            float x2 = x2s[lrow];
            out[(size_t)(row0 + lrow) * C_ + gcol] = dist_val(acc[r], x2, y2, c, scc, inv_sc);
        }
    }
}

extern "C" void kernel_launch(void* const* d_in, const int* in_sizes, int n_in,
                              void* d_out, int out_size, void* d_ws, size_t ws_size,
                              hipStream_t stream) {
    const float* feats  = (const float*)d_in[0];
    const float* protos = (const float*)d_in[1];
    const float* raw_c  = (const float*)d_in[2];
    float* out = (float*)d_out;

    dim3 grid(C_ / 32, B_ / 32);
    fused_kernel<<<grid, 512, 0, stream>>>(feats, protos, raw_c, out);
}